// Round 18
// baseline (40.335 us; speedup 1.0000x reference)
//
#include <hip/hip_runtime.h>
#include <math.h>

#define F_LEN 21
#define D_LEN 41
#define S_LEN 61                 // F_LEN + D_LEN - 1
#define ROWS_W 8                 // rows per wave
#define WAVES 2                  // independent waves per block (no barriers)
#define THREADS 128
#define NELEM_W (ROWS_W * S_LEN) // 488 float2 per wave
#define NV4_W (NELEM_W / 4)      // 122 float4 per array per wave
#define DOUT_W (ROWS_W * D_LEN)  // 328 dist floats per wave
#define DV4_W (DOUT_W / 4)       // 82

// DPP add-reduce within 8-lane groups (VALU only, no LDS pipe).
template <int CTRL>
__device__ __forceinline__ float dpp_add(float x) {
    int y = __builtin_amdgcn_update_dpp(0, __float_as_int(x), CTRL, 0xf, 0xf, true);
    return x + __int_as_float(y);
}
#define DPP_XOR1 0xB1            // quad_perm [1,0,3,2]
#define DPP_XOR2 0x4E            // quad_perm [2,3,0,1]
#define DPP_XOR7 0x141           // row_half_mirror: i -> i^7 within 8-group

#define LGKM0() do { asm volatile("s_waitcnt lgkmcnt(0)" ::: "memory"); \
                     __builtin_amdgcn_sched_barrier(0); } while (0)

// Barrier-free 2-wave blocks: each wave owns 8 rows + a private LDS region.
// 16 blocks/CU x 2 waves = 32 waves/CU (vs 16 for 1-wave blocks, WG/CU cap).
// VGPR<=64 via dl-form lookup: dl[k]=a*tanh(k/(2s)) built cooperatively in
// LDS (cheap trans), 10 regs read back; term = h +- dl*df with h=(pf+pb)/2.
__global__ __launch_bounds__(THREADS, 8) void bp_kernel(
    const float* __restrict__ pf_g, const float* __restrict__ pb_g,
    const float* __restrict__ slop_g, const float* __restrict__ amp_g,
    float* __restrict__ out_dist, float* __restrict__ out_mean,
    float* __restrict__ out_ivar)
{
    __shared__ float2 lds_fb[WAVES][NELEM_W];     // 7808 B; reused for dist
    __shared__ float  dlL[WAVES][ROWS_W * 10];    // 640 B

    const int tid  = threadIdx.x;
    const int w    = tid >> 6;                    // wave 0/1
    const int lane = tid & 63;
    const int rl   = lane >> 3;                   // local row 0..7
    const int q    = lane & 7;                    // octant within row
    const int wrow0 = blockIdx.x * (WAVES * ROWS_W) + w * ROWS_W;
    const int r    = wrow0 + rl;

    float2* fbW = lds_fb[w];
    float*  dlW = dlL[w];

    // ---- staging: float4 global loads -> interleaved float2 LDS (wave-priv)
    const float4* pf4 = (const float4*)(pf_g + (size_t)wrow0 * S_LEN);
    const float4* pb4 = (const float4*)(pb_g + (size_t)wrow0 * S_LEN);
    #pragma unroll
    for (int it = 0; it < 2; ++it) {
        int idx4 = it * 64 + lane;                // 0..127
        if (idx4 < NV4_W) {
            float4 f = pf4[idx4];
            float4 b = pb4[idx4];
            fbW[idx4 * 4 + 0] = make_float2(f.x, b.x);
            fbW[idx4 * 4 + 1] = make_float2(f.y, b.y);
            fbW[idx4 * 4 + 2] = make_float2(f.z, b.z);
            fbW[idx4 * 4 + 3] = make_float2(f.w, b.w);
        }
    }

    // ---- per-row scalars + cooperative dl build (under staging latency) --
    const float a  = amp_g[r];
    const float sl = slop_g[r];
    {
        float* dlp = dlW + rl * 10;
        const int k = q + 1;                      // k = 1..8 -> idx q
        float Ek = __expf((float)k / sl);
        float t  = __fdividef(Ek - 1.0f, Ek + 1.0f);
        dlp[q] = a * t;
        if (q < 2) {
            const int k2 = q + 9;                 // k = 9,10 -> idx 8+q
            float Ek2 = __expf((float)k2 / sl);
            float t2  = __fdividef(Ek2 - 1.0f, Ek2 + 1.0f);
            dlp[8 + q] = a * t2;
        }
    }

    LGKM0();                                      // wave-local: writes visible

    // ---- read back dl[1..10] as 5 aligned float2 -> 10 regs --------------
    float dl_[10];
    {
        const float2* dp2 = (const float2*)(dlW + rl * 10);
        float2 p0 = dp2[0], p1 = dp2[1], p2 = dp2[2], p3 = dp2[3], p4 = dp2[4];
        dl_[0] = p0.x; dl_[1] = p0.y; dl_[2] = p1.x; dl_[3] = p1.y;
        dl_[4] = p2.x; dl_[5] = p2.y; dl_[6] = p3.x; dl_[7] = p3.y;
        dl_[8] = p4.x; dl_[9] = p4.y;
    }

    // ---- column-streaming product over this thread's window --------------
    const int  d0   = q * 5;
    const bool has6 = (q == 7);
    const int  base = rl * S_LEN + d0;

    float prod[6] = {1.0f, 1.0f, 1.0f, 1.0f, 1.0f, 1.0f};
    #pragma unroll
    for (int i = 0; i < 26; ++i) {                // column s = d0 + i
        float2 fb = fbW[base + i];                // one ds_read_b64
        float  df = fb.x - fb.y;
        float  h  = fmaf(0.5f, df, fb.y);         // (pf+pb)/2
        #pragma unroll
        for (int dp = 0; dp < 6; ++dp) {
            const int j = i - dp;                 // compile-time constant
            if (j >= 0 && j < F_LEN) {
                float t;
                if (j == 10)      t = h;
                else if (j < 10)  t = fmaf(dl_[9 - j],  df, h);  // lf=0.5+dl
                else              t = fmaf(dl_[j - 11], -df, h); // lf=0.5-dl
                if (dp == 5) t = has6 ? t : 1.0f;
                prod[dp] *= t;
            }
        }
    }

    // ---- partial moments + 8-lane DPP butterfly --------------------------
    const float df0 = (float)d0;
    float s0 = 0.0f, s1 = 0.0f, s2 = 0.0f;
    #pragma unroll
    for (int dp = 0; dp < 6; ++dp) {
        float p = prod[dp];
        if (dp == 5) p = has6 ? p : 0.0f;
        float dv = df0 + (float)dp;
        s0 += p;
        s1 += dv * p;
        s2 += dv * dv * p;
    }
    s0 = dpp_add<DPP_XOR1>(s0); s0 = dpp_add<DPP_XOR2>(s0); s0 = dpp_add<DPP_XOR7>(s0);
    s1 = dpp_add<DPP_XOR1>(s1); s1 = dpp_add<DPP_XOR2>(s1); s1 = dpp_add<DPP_XOR7>(s1);
    s2 = dpp_add<DPP_XOR1>(s2); s2 = dpp_add<DPP_XOR2>(s2); s2 = dpp_add<DPP_XOR7>(s2);

    const float inv      = 1.0f / fmaxf(s0, 1e-12f);
    const float mean_tmp = s1 * inv;
    const float m2       = s2 * inv;
    const float var_tmp  = fmaf(-mean_tmp, mean_tmp, m2);

    if (q == 0) {
        const float two_a = 2.0f * a;
        const float at    = 0.5f * __logf((1.0f + two_a) / (1.0f - two_a));
        const float min_v = fmaxf(0.5f / (at * at), sl);
        const float var   = fmaxf(var_tmp, min_v);
        out_mean[r] = mean_tmp - (float)((D_LEN - 1) / 2);
        out_ivar[r] = 1.0f / var;
    }

    // ---- dist: stage normalized values in wave-private LDS, float4 out ---
    LGKM0();                                      // fbW reads retired
    float* ldsd = (float*)fbW;                    // alias: 328 floats needed
    #pragma unroll
    for (int dp = 0; dp < 5; ++dp)
        ldsd[rl * D_LEN + d0 + dp] = prod[dp] * inv;
    if (has6)
        ldsd[rl * D_LEN + 40] = prod[5] * inv;

    LGKM0();                                      // cross-lane writes visible
    const float4* ld4 = (const float4*)ldsd;
    float4* o4 = (float4*)(out_dist + (size_t)wrow0 * D_LEN);  // 16B aligned
    #pragma unroll
    for (int it = 0; it < 2; ++it) {
        int idx4 = it * 64 + lane;                // 0..127
        if (idx4 < DV4_W) o4[idx4] = ld4[idx4];
    }
}

extern "C" void kernel_launch(void* const* d_in, const int* in_sizes, int n_in,
                              void* d_out, int out_size, void* d_ws, size_t ws_size,
                              hipStream_t stream) {
    // inputs: [0] lines_feature (unused), [1] pf, [2] pb, [3] slop, [4] amp
    const float* pf   = (const float*)d_in[1];
    const float* pb   = (const float*)d_in[2];
    const float* slop = (const float*)d_in[3];
    const float* amp  = (const float*)d_in[4];

    const int rows = in_sizes[3];              // B * L = 131072

    float* out_dist = (float*)d_out;
    float* out_mean = out_dist + (size_t)rows * D_LEN;
    float* out_ivar = out_mean + rows;

    const int blocks = rows / (WAVES * ROWS_W);   // 8192
    bp_kernel<<<blocks, THREADS, 0, stream>>>(pf, pb, slop, amp,
                                              out_dist, out_mean, out_ivar);
}

// Round 19
// 25.028 us; speedup vs baseline: 1.6116x; 1.6116x over previous
//
#include <hip/hip_runtime.h>
#include <math.h>

#define F_LEN 21
#define D_LEN 41
#define S_LEN 61                 // F_LEN + D_LEN - 1
#define ROWS_W 8                 // rows per wave
#define WAVES 2                  // independent waves per block (no barriers)
#define THREADS 128
#define NELEM_W (ROWS_W * S_LEN) // 488 float2 per wave
#define NV4_W (NELEM_W / 4)      // 122 float4 per array per wave
#define DOUT_W (ROWS_W * D_LEN)  // 328 dist floats per wave
#define DV4_W (DOUT_W / 4)       // 82

// DPP add-reduce within 8-lane groups (VALU only, no LDS pipe).
template <int CTRL>
__device__ __forceinline__ float dpp_add(float x) {
    int y = __builtin_amdgcn_update_dpp(0, __float_as_int(x), CTRL, 0xf, 0xf, true);
    return x + __int_as_float(y);
}
#define DPP_XOR1 0xB1            // quad_perm [1,0,3,2]
#define DPP_XOR2 0x4E            // quad_perm [2,3,0,1]
#define DPP_XOR7 0x141           // row_half_mirror: i -> i^7 within 8-group

#define LGKM0() do { asm volatile("s_waitcnt lgkmcnt(0)" ::: "memory"); \
                     __builtin_amdgcn_sched_barrier(0); } while (0)

// R18 body; ONLY change: __launch_bounds__(128,4) -- the (*,8) bounds made
// the allocator collapse to 32 VGPR and spill (4/4 regressions, WRITE tell).
// Natural allocation of this low-footprint body should land 48-64 VGPR ->
// hardware can still co-resident 8 blocks x 2 waves = 32 waves/CU.
__global__ __launch_bounds__(THREADS, 4) void bp_kernel(
    const float* __restrict__ pf_g, const float* __restrict__ pb_g,
    const float* __restrict__ slop_g, const float* __restrict__ amp_g,
    float* __restrict__ out_dist, float* __restrict__ out_mean,
    float* __restrict__ out_ivar)
{
    __shared__ float2 lds_fb[WAVES][NELEM_W];     // 7808 B; reused for dist
    __shared__ float  dlL[WAVES][ROWS_W * 10];    // 640 B

    const int tid  = threadIdx.x;
    const int w    = tid >> 6;                    // wave 0/1
    const int lane = tid & 63;
    const int rl   = lane >> 3;                   // local row 0..7
    const int q    = lane & 7;                    // octant within row
    const int wrow0 = blockIdx.x * (WAVES * ROWS_W) + w * ROWS_W;
    const int r    = wrow0 + rl;

    float2* fbW = lds_fb[w];
    float*  dlW = dlL[w];

    // ---- staging: float4 global loads -> interleaved float2 LDS (wave-priv)
    const float4* pf4 = (const float4*)(pf_g + (size_t)wrow0 * S_LEN);
    const float4* pb4 = (const float4*)(pb_g + (size_t)wrow0 * S_LEN);
    #pragma unroll
    for (int it = 0; it < 2; ++it) {
        int idx4 = it * 64 + lane;                // 0..127
        if (idx4 < NV4_W) {
            float4 f = pf4[idx4];
            float4 b = pb4[idx4];
            fbW[idx4 * 4 + 0] = make_float2(f.x, b.x);
            fbW[idx4 * 4 + 1] = make_float2(f.y, b.y);
            fbW[idx4 * 4 + 2] = make_float2(f.z, b.z);
            fbW[idx4 * 4 + 3] = make_float2(f.w, b.w);
        }
    }

    // ---- per-row scalars + cooperative dl build (under staging latency) --
    const float a  = amp_g[r];
    const float sl = slop_g[r];
    {
        float* dlp = dlW + rl * 10;
        const int k = q + 1;                      // k = 1..8 -> idx q
        float Ek = __expf((float)k / sl);
        float t  = __fdividef(Ek - 1.0f, Ek + 1.0f);
        dlp[q] = a * t;
        if (q < 2) {
            const int k2 = q + 9;                 // k = 9,10 -> idx 8+q
            float Ek2 = __expf((float)k2 / sl);
            float t2  = __fdividef(Ek2 - 1.0f, Ek2 + 1.0f);
            dlp[8 + q] = a * t2;
        }
    }

    LGKM0();                                      // wave-local: writes visible

    // ---- read back dl[1..10] as 5 aligned float2 -> 10 regs --------------
    float dl_[10];
    {
        const float2* dp2 = (const float2*)(dlW + rl * 10);
        float2 p0 = dp2[0], p1 = dp2[1], p2 = dp2[2], p3 = dp2[3], p4 = dp2[4];
        dl_[0] = p0.x; dl_[1] = p0.y; dl_[2] = p1.x; dl_[3] = p1.y;
        dl_[4] = p2.x; dl_[5] = p2.y; dl_[6] = p3.x; dl_[7] = p3.y;
        dl_[8] = p4.x; dl_[9] = p4.y;
    }

    // ---- column-streaming product over this thread's window --------------
    const int  d0   = q * 5;
    const bool has6 = (q == 7);
    const int  base = rl * S_LEN + d0;

    float prod[6] = {1.0f, 1.0f, 1.0f, 1.0f, 1.0f, 1.0f};
    #pragma unroll
    for (int i = 0; i < 26; ++i) {                // column s = d0 + i
        float2 fb = fbW[base + i];                // one ds_read_b64
        float  df = fb.x - fb.y;
        float  h  = fmaf(0.5f, df, fb.y);         // (pf+pb)/2
        #pragma unroll
        for (int dp = 0; dp < 6; ++dp) {
            const int j = i - dp;                 // compile-time constant
            if (j >= 0 && j < F_LEN) {
                float t;
                if (j == 10)      t = h;
                else if (j < 10)  t = fmaf(dl_[9 - j],  df, h);  // lf=0.5+dl
                else              t = fmaf(dl_[j - 11], -df, h); // lf=0.5-dl
                if (dp == 5) t = has6 ? t : 1.0f;
                prod[dp] *= t;
            }
        }
    }

    // ---- partial moments + 8-lane DPP butterfly --------------------------
    const float df0 = (float)d0;
    float s0 = 0.0f, s1 = 0.0f, s2 = 0.0f;
    #pragma unroll
    for (int dp = 0; dp < 6; ++dp) {
        float p = prod[dp];
        if (dp == 5) p = has6 ? p : 0.0f;
        float dv = df0 + (float)dp;
        s0 += p;
        s1 += dv * p;
        s2 += dv * dv * p;
    }
    s0 = dpp_add<DPP_XOR1>(s0); s0 = dpp_add<DPP_XOR2>(s0); s0 = dpp_add<DPP_XOR7>(s0);
    s1 = dpp_add<DPP_XOR1>(s1); s1 = dpp_add<DPP_XOR2>(s1); s1 = dpp_add<DPP_XOR7>(s1);
    s2 = dpp_add<DPP_XOR1>(s2); s2 = dpp_add<DPP_XOR2>(s2); s2 = dpp_add<DPP_XOR7>(s2);

    const float inv      = 1.0f / fmaxf(s0, 1e-12f);
    const float mean_tmp = s1 * inv;
    const float m2       = s2 * inv;
    const float var_tmp  = fmaf(-mean_tmp, mean_tmp, m2);

    if (q == 0) {
        const float two_a = 2.0f * a;
        const float at    = 0.5f * __logf((1.0f + two_a) / (1.0f - two_a));
        const float min_v = fmaxf(0.5f / (at * at), sl);
        const float var   = fmaxf(var_tmp, min_v);
        out_mean[r] = mean_tmp - (float)((D_LEN - 1) / 2);
        out_ivar[r] = 1.0f / var;
    }

    // ---- dist: stage normalized values in wave-private LDS, float4 out ---
    LGKM0();                                      // fbW reads retired
    float* ldsd = (float*)fbW;                    // alias: 328 floats needed
    #pragma unroll
    for (int dp = 0; dp < 5; ++dp)
        ldsd[rl * D_LEN + d0 + dp] = prod[dp] * inv;
    if (has6)
        ldsd[rl * D_LEN + 40] = prod[5] * inv;

    LGKM0();                                      // cross-lane writes visible
    const float4* ld4 = (const float4*)ldsd;
    float4* o4 = (float4*)(out_dist + (size_t)wrow0 * D_LEN);  // 16B aligned
    #pragma unroll
    for (int it = 0; it < 2; ++it) {
        int idx4 = it * 64 + lane;                // 0..127
        if (idx4 < DV4_W) o4[idx4] = ld4[idx4];
    }
}

extern "C" void kernel_launch(void* const* d_in, const int* in_sizes, int n_in,
                              void* d_out, int out_size, void* d_ws, size_t ws_size,
                              hipStream_t stream) {
    // inputs: [0] lines_feature (unused), [1] pf, [2] pb, [3] slop, [4] amp
    const float* pf   = (const float*)d_in[1];
    const float* pb   = (const float*)d_in[2];
    const float* slop = (const float*)d_in[3];
    const float* amp  = (const float*)d_in[4];

    const int rows = in_sizes[3];              // B * L = 131072

    float* out_dist = (float*)d_out;
    float* out_mean = out_dist + (size_t)rows * D_LEN;
    float* out_ivar = out_mean + rows;

    const int blocks = rows / (WAVES * ROWS_W);   // 8192
    bp_kernel<<<blocks, THREADS, 0, stream>>>(pf, pb, slop, amp,
                                              out_dist, out_mean, out_ivar);
}